// Round 14
// baseline (390.813 us; speedup 1.0000x reference)
//
#include <hip/hip_runtime.h>
#include <hip/hip_bf16.h>
#include <cstdint>

// Problem constants
#define B_ 4
#define S_ 4096
#define D_ 1024
#define DFF_ 4096
#define KSEL_ 2048
#define M_ (B_ * KSEL_)      // 8192 selected rows total
#define NTOK_ (B_ * S_)      // 16384

typedef short bf16x8 __attribute__((ext_vector_type(8)));
typedef float f32x4 __attribute__((ext_vector_type(4)));

__device__ inline unsigned short f2bf(float f) {
    union { float f; unsigned int u; } c; c.f = f;
    unsigned int u = c.u;
    unsigned int r = u + 0x7fffu + ((u >> 16) & 1u);
    return (unsigned short)(r >> 16);
}

// ---------------------------------------------------------------------------
// Fused transpose + fp32->bf16 for W1 and W2 in ONE launch.
// ---------------------------------------------------------------------------
__global__ __launch_bounds__(256)
void transpose2_bf16(const float* __restrict__ W1, unsigned short* __restrict__ W1bT,
                     const float* __restrict__ W2, unsigned short* __restrict__ W2bT) {
    __shared__ float tile[32][33];
    int id = blockIdx.x;
    const float* src; unsigned short* dst; int R, C, bx, by;
    if (id < (DFF_ / 32) * (D_ / 32)) {
        src = W1; dst = W1bT; R = D_; C = DFF_;
        bx = id % (DFF_ / 32); by = id / (DFF_ / 32);
    } else {
        id -= (DFF_ / 32) * (D_ / 32);
        src = W2; dst = W2bT; R = DFF_; C = D_;
        bx = id % (D_ / 32); by = id / (D_ / 32);
    }
    int c0 = bx * 32, r0 = by * 32;
    for (int i = threadIdx.y; i < 32; i += 8)
        tile[i][threadIdx.x] = src[(size_t)(r0 + i) * C + c0 + threadIdx.x];
    __syncthreads();
    for (int i = threadIdx.y; i < 32; i += 8)
        dst[(size_t)(c0 + i) * R + r0 + threadIdx.x] = f2bf(tile[threadIdx.x][i]);
}

// ---------------------------------------------------------------------------
// Router: logits[row] = dot(x[row], Wr); write xb = bf16(x); write out = x
// ---------------------------------------------------------------------------
__global__ __launch_bounds__(256)
void router_kernel(const float* __restrict__ x, const float* __restrict__ Wr,
                   float* __restrict__ logits, unsigned short* __restrict__ xb,
                   float* __restrict__ out) {
    int wid = threadIdx.x >> 6, lane = threadIdx.x & 63;
    int row = blockIdx.x * 4 + wid;
    const float* xr = x + (size_t)row * D_;
    unsigned short* xbr = xb + (size_t)row * D_;
    float* outr = out + (size_t)row * D_;
    float acc = 0.f;
#pragma unroll
    for (int j = 0; j < 4; j++) {
        int off = j * 256 + lane * 4;
        float4 v = *(const float4*)(xr + off);
        float4 w = *(const float4*)(Wr + off);
        acc += v.x * w.x + v.y * w.y + v.z * w.z + v.w * w.w;
        *(float4*)(outr + off) = v;
        ushort4 o;
        o.x = f2bf(v.x); o.y = f2bf(v.y); o.z = f2bf(v.z); o.w = f2bf(v.w);
        *(ushort4*)(xbr + off) = o;
    }
#pragma unroll
    for (int s = 32; s; s >>= 1) acc += __shfl_xor(acc, s);
    if (lane == 0) logits[row] = acc;
}

// ---------------------------------------------------------------------------
// Rank (split-j): partial rank over a 512-logit j-chunk, atomicAdd into rank[].
// ---------------------------------------------------------------------------
__global__ __launch_bounds__(256)
void rank_partial_kernel(const float* __restrict__ logits, int* __restrict__ rank) {
    __shared__ float lj[512];
    int b  = blockIdx.x >> 7;
    int ic = (blockIdx.x >> 3) & 15;
    int jc = blockIdx.x & 7;
    const float* L = logits + b * S_;
    for (int t = threadIdx.x; t < 512; t += 256) lj[t] = L[jc * 512 + t];
    __syncthreads();
    int i = ic * 256 + threadIdx.x;
    float li = L[i];
    int jbase = jc * 512;
    int r = 0;
    const float4* __restrict__ lj4 = (const float4*)lj;
#pragma unroll 4
    for (int q = 0; q < 128; q++) {
        float4 v = lj4[q];
        int jb = jbase + q * 4;
        r += (v.x > li) | ((v.x == li) & (jb     < i));
        r += (v.y > li) | ((v.y == li) & (jb + 1 < i));
        r += (v.z > li) | ((v.z == li) & (jb + 2 < i));
        r += (v.w > li) | ((v.w == li) & (jb + 3 < i));
    }
    atomicAdd(&rank[b * S_ + i], r);
}

// ---------------------------------------------------------------------------
// Compact: sel = rank < KSEL_; flags, softmax weights, prefix-sum -> rowidx/rw.
// ---------------------------------------------------------------------------
__global__ __launch_bounds__(256)
void compact_kernel(const float* __restrict__ logits, const int* __restrict__ rank,
                    int* __restrict__ flags,
                    int* __restrict__ rowidx, float* __restrict__ rw) {
    __shared__ float lg[S_];
    __shared__ int f[S_];
    __shared__ int tsum[256];
    __shared__ float red[256];
    int b = blockIdx.x;
    const float* L = logits + b * S_;
    const int* R = rank + b * S_;
    int* F = flags + b * S_;
    for (int j = threadIdx.x; j < S_ / 4; j += 256) {
        ((float4*)lg)[j] = ((const float4*)L)[j];
        int4 rk = ((const int4*)R)[j];
        int4 fl;
        fl.x = rk.x < KSEL_; fl.y = rk.y < KSEL_;
        fl.z = rk.z < KSEL_; fl.w = rk.w < KSEL_;
        ((int4*)f)[j] = fl;
        ((int4*)F)[j] = fl;
    }
    __syncthreads();
    float mx = -INFINITY;
    for (int j = threadIdx.x; j < S_; j += 256) mx = fmaxf(mx, lg[j]);
    red[threadIdx.x] = mx; __syncthreads();
    for (int s = 128; s; s >>= 1) {
        if (threadIdx.x < s) red[threadIdx.x] = fmaxf(red[threadIdx.x], red[threadIdx.x + s]);
        __syncthreads();
    }
    float m = red[0];
    __syncthreads();

    float esum = 0.f;
    int s0 = 0;
#pragma unroll
    for (int j = 0; j < 16; j++) {
        int i = threadIdx.x * 16 + j;
        s0 += f[i];
        if (f[i]) esum += expf(lg[i] - m);
    }
    red[threadIdx.x] = esum; __syncthreads();
    for (int s = 128; s; s >>= 1) {
        if (threadIdx.x < s) red[threadIdx.x] += red[threadIdx.x + s];
        __syncthreads();
    }
    float inv = 1.f / red[0];

    tsum[threadIdx.x] = s0; __syncthreads();
    for (int s = 1; s < 256; s <<= 1) {
        int u = (threadIdx.x >= s) ? tsum[threadIdx.x - s] : 0;
        __syncthreads();
        tsum[threadIdx.x] += u;
        __syncthreads();
    }
    int pos = tsum[threadIdx.x] - s0;
    for (int j = 0; j < 16; j++) {
        int i = threadIdx.x * 16 + j;
        if (f[i]) {
            rowidx[b * KSEL_ + pos] = b * S_ + i;
            rw[b * KSEL_ + pos] = expf(lg[i] - m) * inv;
            pos++;
        }
    }
}

// ---------------------------------------------------------------------------
// Aux loss (round-7 proven 2-kernel form): BCE-with-logits mean.
// ---------------------------------------------------------------------------
__global__ __launch_bounds__(256)
void loss_kernel(const float* __restrict__ logits, const int* __restrict__ flags,
                 float* __restrict__ partials) {
    __shared__ float red[256];
    int i = blockIdx.x * 256 + threadIdx.x;
    float l = logits[i];
    float t = 0.f;
    if (i < S_)
        t = (flags[i] | flags[S_ + i] | flags[2 * S_ + i] | flags[3 * S_ + i]) ? 1.f : 0.f;
    float v = fmaxf(l, 0.f) - l * t + log1pf(expf(-fabsf(l)));
    red[threadIdx.x] = v; __syncthreads();
    for (int s = 128; s; s >>= 1) {
        if (threadIdx.x < s) red[threadIdx.x] += red[threadIdx.x + s];
        __syncthreads();
    }
    if (threadIdx.x == 0) partials[blockIdx.x] = red[0];
}

__global__ void loss_final(const float* __restrict__ partials, float* __restrict__ out) {
    float v = partials[threadIdx.x];
#pragma unroll
    for (int s = 32; s; s >>= 1) v += __shfl_xor(v, s);
    if (threadIdx.x == 0) out[0] = v / (float)NTOK_;
}

// ---------------------------------------------------------------------------
// GEMM1 m201-faithful port: 256x256 tile, BK=64 K-tiles, 8 phases / 2 tiles.
// 8 waves (2M x 4N), per-wave 128x64, acc[8][4].  2-slot dbuf x 2 halves:
// As[slot][half][128][64], Bs same = 128 KiB.  Tile t uses slot t&1.
// B-IN-REGS: bfr[4][2] read once per K-tile (phase mb==0: 12 ds_reads),
// phases 1-3 read only af (4 ds_reads) -> 3 of 4 phases are LDS-light.
// One half-tile (2 global_load_lds) staged per phase, death-ordered
// (target half's last LDS read finished >=1 barrier before stage issue):
//   p0: A.h0(t+1)  [slot1.A last read prev-iter p7]    p4: A.h0(t+2) [slot0.A last read p3]
//   p1: A.h1(t+1)                                      p5: A.h1(t+2)
//   p2: B.h0(t+2)  [slot0.B read only at p0]           p6: B.h0(t+3) [slot1.B read only at p4]
//   p3: B.h1(t+2)                                      p7: B.h1(t+3)
// Counted waits ONLY at p3/p7 (once per K-tile), never 0 mid-loop:
//   end-p3: vmcnt(4) -> 8 oldest (B(t+1), A(t+1)) done before p4 reads slot1;
//           the 4 newest (B(t+2)) stay in flight.
//   end-p7: vmcnt(4) -> B(t+2)+A(t+2) done before next iter reads slot0;
//           B(t+3) floats.  Tails degrade to vmcnt(0).
// Mid-loop flush stores increment vmcnt but are OLDER than the newest 4 at
// every later counted wait -> invariant (tile t+1 landed) still guaranteed;
// the store-drain is a one-time accepted bubble.
// vmcnt precedes s_barrier -> every wave's own loads done before any wave
// crosses.  LDS dest of global_load_lds is WAVE-UNIFORM (w-only terms);
// lanes land at base+lane*16 (m104 semantics; matches proven gemm_pipe).
// Swizzle: bit-identical involution to proven gemm_pipe (BK=64 = 128-B rows,
// source chunk sw=(lane&7)^srow; read xo=(kc^(lr&7))*16; measured 0 conflicts).
// Epilogue: verified gemm1_256 flush (silu + bf16).
// ---------------------------------------------------------------------------
template <int N, int K, int SUBS>
__global__ __launch_bounds__(512, 2)
void gemm1_8p_kernel(const unsigned short* __restrict__ A,
                     const unsigned short* __restrict__ BT,
                     const int* __restrict__ rowidx,
                     unsigned short* __restrict__ Hout) {
    static_assert(SUBS == 2, "address selection hardcoded for SUBS=2");
    constexpr int BK = 64;
    constexpr int KT = K / BK;              // 16 K-tiles per subtile
    constexpr int TT = SUBS * KT;           // 32 tiles total
    constexpr int NT = N / 256;             // 16
    constexpr int MG = M_ / (256 * SUBS);   // 16
    constexpr int NWG = NT * MG;            // 256
    constexpr int CPX = NWG / 8;
    __shared__ __attribute__((aligned(16))) unsigned short As[2][2][128 * BK];
    __shared__ __attribute__((aligned(16))) unsigned short Bs[2][2][128 * BK];

    const int tid = threadIdx.x;
    const int w = tid >> 6, lane = tid & 63;
    const int wm = w >> 2, wn = w & 3;      // 2M x 4N waves

    // bijective XCD swizzle, n fastest within an XCD
    int wgid = blockIdx.y * NT + blockIdx.x;
    int swz = (wgid & 7) * CPX + (wgid >> 3);
    const int tile_n = (swz % NT) * 256;
    const int mgrp   = swz / NT;

    // staging global addresses (proven gemm_pipe pattern): one gload covers
    // 64 rows (8/wave); half = 2 gloads (h = half*2+g covers rows h*64..+63).
    const int srow = lane >> 3;
    const int sw = (lane & 7) ^ srow;
    const uint64_t abase = (uint64_t)(uintptr_t)A;
    const uint64_t bbase = (uint64_t)(uintptr_t)BT;
    uint64_t aaddr0[4], aaddr1[4], baddr[4];
#pragma unroll
    for (int h = 0; h < 4; ++h) {
        int r0 = (mgrp * SUBS + 0) * 256 + h * 64 + w * 8 + srow;
        int r1 = (mgrp * SUBS + 1) * 256 + h * 64 + w * 8 + srow;
        aaddr0[h] = abase + ((uint64_t)rowidx[r0] * K + (uint64_t)sw * 8) * 2ull;
        aaddr1[h] = abase + ((uint64_t)rowidx[r1] * K + (uint64_t)sw * 8) * 2ull;
        int rb = tile_n + h * 64 + w * 8 + srow;
        baddr[h] = bbase + ((uint64_t)rb * K + (uint64_t)sw * 8) * 2ull;
    }

    auto gload = [&](unsigned short* lds, uint64_t gaddr) {
        __builtin_amdgcn_global_load_lds(
            (const __attribute__((address_space(1))) unsigned int*)(uintptr_t)gaddr,
            (__attribute__((address_space(3))) unsigned int*)lds, 16, 0, 0);
    };
    // LDS dest: WAVE-UNIFORM base (w-only); lanes land at +lane*16B.
    auto stageAh = [&](int tt, int half) {
        const uint64_t koff = (uint64_t)(tt & (KT - 1)) * (BK * 2);
        const int slot = tt & 1;
#pragma unroll
        for (int g = 0; g < 2; ++g) {
            const uint64_t a = (tt >= KT) ? aaddr1[half * 2 + g] : aaddr0[half * 2 + g];
            gload(&As[slot][half][(g * 64 + w * 8) * BK], a + koff);
        }
    };
    auto stageBh = [&](int tt, int half) {
        const uint64_t koff = (uint64_t)(tt & (KT - 1)) * (BK * 2);
        const int slot = tt & 1;
#pragma unroll
        for (int g = 0; g < 2; ++g)
            gload(&Bs[slot][half][(g * 64 + w * 8) * BK], baddr[half * 2 + g] + koff);
    };

    f32x4 acc[8][4];
#pragma unroll
    for (int i = 0; i < 8; i++)
#pragma unroll
        for (int j = 0; j < 4; j++) acc[i][j] = (f32x4){0.f, 0.f, 0.f, 0.f};

    const int lr = lane & 15, quad = lane >> 4;

    auto flush = [&](int s) {
        const int tm = (mgrp * SUBS + s) * 256 + wm * 128;
#pragma unroll
        for (int m4 = 0; m4 < 8; ++m4)
#pragma unroll
            for (int r = 0; r < 4; ++r) {
                int m = tm + m4 * 16 + quad * 4 + r;
#pragma unroll
                for (int n4 = 0; n4 < 4; ++n4) {
                    int col = tile_n + wn * 64 + n4 * 16 + lr;
                    float v = acc[m4][n4][r];
                    v = v / (1.f + __expf(-v));   // silu
                    Hout[(uint64_t)m * N + col] = f2bf(v);
                }
            }
    };

    // prologue: T0 fully + T1.B = 12 gloads; vmcnt(4) -> T0's 8 complete,
    // T1.B's 4 float.  T1.A staged at p0/p1.
    stageAh(0, 0); stageAh(0, 1); stageBh(0, 0); stageBh(0, 1);
    stageBh(1, 0); stageBh(1, 1);
    asm volatile("s_waitcnt vmcnt(4)" ::: "memory");
    asm volatile("s_barrier" ::: "memory");

#pragma unroll 1
    for (int it = 0; it < TT / 2; ++it) {
        const int t = 2 * it;
#pragma unroll
        for (int tp = 0; tp < 2; ++tp) {
            const int slot = tp;            // tile t+tp -> slot (t+tp)&1 == tp
            bf16x8 bfr[4][2];
#pragma unroll
            for (int mb = 0; mb < 4; ++mb) {
                // ---- ds-read register subtile ----
                bf16x8 af[2][2];
#pragma unroll
                for (int d = 0; d < 2; ++d)
#pragma unroll
                    for (int kk = 0; kk < 2; ++kk) {
                        int lrow = (2 * mb + d) * 16 + lr;
                        int xo = (((kk * 4 + quad) ^ (lr & 7)) * 16);
                        af[d][kk] = *(const bf16x8*)((const char*)&As[slot][wm][0]
                                        + lrow * (BK * 2) + xo);
                    }
                if (mb == 0) {
#pragma unroll
                    for (int n4 = 0; n4 < 4; ++n4)
#pragma unroll
                        for (int kk = 0; kk < 2; ++kk) {
                            int lrow = (wn & 1) * 64 + n4 * 16 + lr;
                            int xo = (((kk * 4 + quad) ^ (lr & 7)) * 16);
                            bfr[n4][kk] = *(const bf16x8*)((const char*)&Bs[slot][wn >> 1][0]
                                            + lrow * (BK * 2) + xo);
                        }
                }
                // ---- stage 1 half-tile (death-ordered schedule) ----
                if (tp == 0) {
                    if (mb == 0)      stageAh(t + 1, 0);
                    else if (mb == 1) stageAh(t + 1, 1);
                    else if (mb == 2) { if (t + 2 < TT) stageBh(t + 2, 0); }
                    else              { if (t + 2 < TT) stageBh(t + 2, 1); }
                } else {
                    if (mb == 0)      { if (t + 2 < TT) stageAh(t + 2, 0); }
                    else if (mb == 1) { if (t + 2 < TT) stageAh(t + 2, 1); }
                    else if (mb == 2) { if (t + 3 < TT) stageBh(t + 3, 0); }
                    else              { if (t + 3 < TT) stageBh(t + 3, 1); }
                }
                // ---- barrier ; lgkmcnt(0) ; MFMA cluster ----
                asm volatile("s_barrier" ::: "memory");
                asm volatile("s_waitcnt lgkmcnt(0)" ::: "memory");
                __builtin_amdgcn_sched_barrier(0);
                __builtin_amdgcn_s_setprio(1);
#pragma unroll
                for (int kk = 0; kk < 2; ++kk)
#pragma unroll
                    for (int d = 0; d < 2; ++d)
#pragma unroll
                        for (int n4 = 0; n4 < 4; ++n4)
                            acc[2 * mb + d][n4] = __builtin_amdgcn_mfma_f32_16x16x32_bf16(
                                af[d][kk], bfr[n4][kk], acc[2 * mb + d][n4], 0, 0, 0);
                __builtin_amdgcn_s_setprio(0);
                // ---- counted wait once per K-tile (end of phase 3 / 7) ----
                if (mb == 3) {
                    if (tp == 0) {
                        if (t + 2 < TT) { asm volatile("s_waitcnt vmcnt(4)" ::: "memory"); }
                        else            { asm volatile("s_waitcnt vmcnt(0)" ::: "memory"); }
                    } else {
                        if (t + 3 < TT) { asm volatile("s_waitcnt vmcnt(4)" ::: "memory"); }
                        else            { asm volatile("s_waitcnt vmcnt(0)" ::: "memory"); }
                    }
                }
                asm volatile("s_barrier" ::: "memory");
            }
        }
        // subtile boundary: tiles 0..KT-1 consumed at end of it = KT/2 - 1
        if (t + 2 == KT) {
            flush(0);
#pragma unroll
            for (int i = 0; i < 8; i++)
#pragma unroll
                for (int j = 0; j < 4; j++) acc[i][j] = (f32x4){0.f, 0.f, 0.f, 0.f};
        }
    }
    flush(SUBS - 1);
}

// ---------------------------------------------------------------------------
// GEMM2 (unchanged, round-7 measured): fine-phased 128x256, 3-slot ring,
// counted vmcnt(6).  MODE 2: scatter x + (H@W2)*rw.
// ---------------------------------------------------------------------------
template <int MODE, int N, int K, int SUBS>
__global__ __launch_bounds__(512, 2)
void gemm_pipe_kernel(const unsigned short* __restrict__ A,
                      const unsigned short* __restrict__ BT,
                      const int* __restrict__ rowidx,
                      const float* __restrict__ rw,
                      const float* __restrict__ x,
                      unsigned short* __restrict__ Hout,
                      float* __restrict__ Out) {
    constexpr int BM = 128, BN = 256, BK = 64;
    constexpr int KI = K / BK;
    constexpr int NT = N / BN;
    constexpr int MG = M_ / (BM * SUBS);
    constexpr int NWG = NT * MG;
    constexpr int CPX = NWG / 8;
    __shared__ __attribute__((aligned(16))) unsigned short As[3][BM * BK];
    __shared__ __attribute__((aligned(16))) unsigned short Bs[3][BN * BK];

    const int tid = threadIdx.x;
    const int w = tid >> 6, lane = tid & 63;
    const int wm = w >> 2, wn = w & 3;

    int wgid = blockIdx.y * NT + blockIdx.x;
    int swz = (wgid & 7) * CPX + (wgid >> 3);
    const int tile_n = (swz % NT) * BN;
    const int mgrp   = (swz / NT);

    const int srow = lane >> 3;
    const int sw = (lane & 7) ^ srow;
    const uint64_t abase = (uint64_t)(uintptr_t)A;
    const uint64_t bbase = (uint64_t)(uintptr_t)BT;
    uint64_t aaddr[SUBS][2], baddr[4];
#pragma unroll
    for (int s = 0; s < SUBS; ++s)
#pragma unroll
        for (int t = 0; t < 2; ++t) {
            int r = t * 64 + w * 8 + srow;
            int am = (mgrp * SUBS + s) * BM + r;
            int ar = (MODE == 1) ? rowidx[am] : am;
            aaddr[s][t] = abase + ((uint64_t)ar * K + (uint64_t)sw * 8) * 2ull;
        }
#pragma unroll
    for (int t = 0; t < 4; ++t) {
        int r = t * 64 + w * 8 + srow;
        baddr[t] = bbase + ((uint64_t)(tile_n + r) * K + (uint64_t)sw * 8) * 2ull;
    }

    auto gload = [&](unsigned short* lds, uint64_t gaddr) {
        __builtin_amdgcn_global_load_lds(
            (const __attribute__((address_space(1))) unsigned int*)(uintptr_t)gaddr,
            (__attribute__((address_space(3))) unsigned int*)lds, 16, 0, 0);
    };

    f32x4 acc[4][4];
#pragma unroll
    for (int i = 0; i < 4; i++)
#pragma unroll
        for (int j = 0; j < 4; j++) acc[i][j] = (f32x4){0.f, 0.f, 0.f, 0.f};

#pragma unroll
    for (int p = 0; p < 2; ++p) {
        const uint64_t koff = (uint64_t)p * (BK * 2);
        gload(&As[p][(0 * 64 + w * 8) * BK], aaddr[0][0] + koff);
        gload(&As[p][(1 * 64 + w * 8) * BK], aaddr[0][1] + koff);
#pragma unroll
        for (int t = 0; t < 4; ++t)
            gload(&Bs[p][(t * 64 + w * 8) * BK], baddr[t] + koff);
    }
    asm volatile("s_waitcnt vmcnt(6)" ::: "memory");
    asm volatile("s_barrier" ::: "memory");

    const int lr = lane & 15, quad = lane >> 4;
    int c = 0;
#pragma unroll
    for (int s = 0; s < SUBS; ++s) {
#pragma unroll 1
        for (int kt = 0; kt < KI; ++kt) {
            int pre = c + 2; if (pre >= 3) pre -= 3;
            const char* Abase_l = (const char*)&As[c][0];
            const char* Bbase_l = (const char*)&Bs[c][0];
            const bool cross = (kt + 2 >= KI);
            const bool do_stage = (s < SUBS - 1) || (kt + 2 < KI);
            const uint64_t sa0 = cross ? aaddr[(s + 1 < SUBS) ? s + 1 : s][0]
                                       : aaddr[s][0];
            const uint64_t sa1 = cross ? aaddr[(s + 1 < SUBS) ? s + 1 : s][1]
                                       : aaddr[s][1];
            const uint64_t koff = (uint64_t)((kt + 2) & (KI - 1)) * (BK * 2);

            // ================= phase 0 : ks = 0 =================
            {
                bf16x8 af[4], bfr[4];
                const int xo = (quad ^ (lr & 7)) * 16;
#pragma unroll
                for (int m4 = 0; m4 < 4; ++m4) {
                    int row = wm * 64 + m4 * 16 + lr;
                    af[m4] = *(const bf16x8*)(Abase_l + row * (BK * 2) + xo);
                }
#pragma unroll
                for (int n4 = 0; n4 < 4; ++n4) {
                    int col = wn * 64 + n4 * 16 + lr;
                    bfr[n4] = *(const bf16x8*)(Bbase_l + col * (BK * 2) + xo);
                }
                if (do_stage) {
                    gload(&As[pre][(0 * 64 + w * 8) * BK], sa0 + koff);
                    gload(&As[pre][(1 * 64 + w * 8) * BK], sa1 + koff);
                    gload(&Bs[pre][(w * 8) * BK], baddr[0] + koff);
                }
                asm volatile("s_barrier" ::: "memory");
                asm volatile("s_waitcnt lgkmcnt(0)" ::: "memory");
                __builtin_amdgcn_sched_barrier(0);
                __builtin_amdgcn_s_setprio(1);
#pragma unroll
                for (int m4 = 0; m4 < 4; ++m4)
#pragma unroll
                    for (int n4 = 0; n4 < 4; ++n4)
                        acc[m4][n4] = __builtin_amdgcn_mfma_f32_16x16x32_bf16(
                            af[m4], bfr[n4], acc[m4][n4], 0, 0, 0);
                __builtin_amdgcn_s_setprio(0);
                asm volatile("s_barrier" ::: "memory");
            }

            // ================= phase 1 : ks = 1 =================
            {
                bf16x8 af[4], bfr[4];
                const int xo = ((4 + quad) ^ (lr & 7)) * 16;
#pragma unroll
                for (int m4 = 0; m4 < 4; ++m4) {
                    int row = wm * 64 + m4 * 16 + lr;
                    af[m4] = *(const bf16x8*)(Abase_l + row * (BK * 2) + xo);
                }
#pragma unroll
                for (int n4 = 0; n4 < 4; ++n4) {
                    int col = wn * 64 + n4 * 16 + lr;
                    bfr[n4] = *(const bf16x8*)(Bbase_l + col * (BK * 2) + xo);
                }
                if (do_stage) {
#pragma unroll
                    for (int t = 1; t < 4; ++t)
                        gload(&Bs[pre][(t * 64 + w * 8) * BK], baddr[t] + koff);
                }
                asm volatile("s_barrier" ::: "memory");
                asm volatile("s_waitcnt lgkmcnt(0)" ::: "memory");
                __builtin_amdgcn_sched_barrier(0);
                __builtin_amdgcn_s_setprio(1);
#pragma unroll
                for (int m4 = 0; m4 < 4; ++m4)
#pragma unroll
                    for (int n4 = 0; n4 < 4; ++n4)
                        acc[m4][n4] = __builtin_amdgcn_mfma_f32_16x16x32_bf16(
                            af[m4], bfr[n4], acc[m4][n4], 0, 0, 0);
                __builtin_amdgcn_s_setprio(0);
                if (do_stage) {
                    asm volatile("s_waitcnt vmcnt(6)" ::: "memory");
                } else if (kt + 2 == KI) {
                    asm volatile("s_waitcnt vmcnt(0)" ::: "memory");
                }
                asm volatile("s_barrier" ::: "memory");
                c += 1; if (c >= 3) c = 0;
            }
        }

        if (MODE == 1) {
            const int tile_m = (mgrp * SUBS + s) * BM;
#pragma unroll
            for (int m4 = 0; m4 < 4; ++m4)
#pragma unroll
                for (int r = 0; r < 4; ++r) {
                    int m = tile_m + wm * 64 + m4 * 16 + quad * 4 + r;
#pragma unroll
                    for (int n4 = 0; n4 < 4; ++n4) {
                        int col = tile_n + wn * 64 + n4 * 16 + lr;
                        float v = acc[m4][n4][r];
                        v = v / (1.f + __expf(-v));
                        Hout[(uint64_t)m * N + col] = f2bf(v);
                    }
                }
            if (s + 1 < SUBS) {
#pragma unroll
                for (int i = 0; i < 4; i++)
#pragma unroll
                    for (int j = 0; j < 4; j++)
                        acc[i][j] = (f32x4){0.f, 0.f, 0.f, 0.f};
            }
        }
    }

    if (MODE == 2) {
        const int tile_m = mgrp * SUBS * BM;
#pragma unroll
        for (int m4 = 0; m4 < 4; ++m4)
#pragma unroll
            for (int r = 0; r < 4; ++r) {
                int m = tile_m + wm * 64 + m4 * 16 + quad * 4 + r;
                int grow = rowidx[m];
                float wgt = rw[m];
                uint64_t rb = (uint64_t)grow * D_;
#pragma unroll
                for (int n4 = 0; n4 < 4; ++n4) {
                    int col = tile_n + wn * 64 + n4 * 16 + lr;
                    Out[rb + col] = x[rb + col] + acc[m4][n4][r] * wgt;
                }
            }
    }
}

// ---------------------------------------------------------------------------
extern "C" void kernel_launch(void* const* d_in, const int* in_sizes, int n_in,
                              void* d_out, int out_size, void* d_ws, size_t ws_size,
                              hipStream_t stream) {
    const float* x  = (const float*)d_in[0];
    // d_in[1] = mask (unused: all-ones in setup, MLP ignores it)
    const float* Wr = (const float*)d_in[2];
    const float* W1 = (const float*)d_in[3];
    const float* W2 = (const float*)d_in[4];
    float* out = (float*)d_out;

    char* ws = (char*)d_ws;
    size_t off = 0;
    auto alloc = [&](size_t bytes) {
        char* p = ws + off;
        off = (off + bytes + 255) & ~(size_t)255;
        return p;
    };
    unsigned short* xb   = (unsigned short*)alloc((size_t)NTOK_ * D_ * 2);  // 33.5 MB
    unsigned short* W1bT = (unsigned short*)alloc((size_t)DFF_ * D_ * 2);   // 8.4 MB
    unsigned short* W2bT = (unsigned short*)alloc((size_t)D_ * DFF_ * 2);   // 8.4 MB
    unsigned short* H    = (unsigned short*)alloc((size_t)M_ * DFF_ * 2);   // 67 MB
    float* logits  = (float*)alloc(NTOK_ * 4);
    int*   rank    = (int*)alloc(NTOK_ * 4);
    int*   flags   = (int*)alloc(NTOK_ * 4);
    int*   rowidx  = (int*)alloc(M_ * 4);
    float* rwp     = (float*)alloc(M_ * 4);
    float* partials = (float*)alloc(64 * 4);

    (void)hipMemsetAsync(rank, 0, NTOK_ * 4, stream);

    transpose2_bf16<<<2 * (DFF_ / 32) * (D_ / 32), dim3(32, 8), 0, stream>>>(
        W1, W1bT, W2, W2bT);
    router_kernel<<<NTOK_ / 4, 256, 0, stream>>>(x, Wr, logits, xb, out);
    rank_partial_kernel<<<512, 256, 0, stream>>>(logits, rank);
    compact_kernel<<<B_, 256, 0, stream>>>(logits, rank, flags, rowidx, rwp);
    loss_kernel<<<NTOK_ / 256, 256, 0, stream>>>(logits, flags, partials);
    loss_final<<<1, 64, 0, stream>>>(partials, out + (size_t)NTOK_ * D_);
    // GEMM1: H[8192][4096] = silu(gather(xb) @ W1)  -- m201 8-phase port
    gemm1_8p_kernel<DFF_, D_, 2><<<dim3(DFF_ / 256, M_ / 512), 512, 0, stream>>>(
        xb, W1bT, rowidx, H);
    // GEMM2: out[rowidx[m]] = x[rowidx[m]] + (H @ W2)[m] * rw[m]
    gemm_pipe_kernel<2, D_, DFF_, 1><<<dim3(D_ / 256, M_ / 128), 512, 0, stream>>>(
        H, W2bT, rowidx, rwp, x, nullptr, out);
}